// Round 7
// baseline (184.353 us; speedup 1.0000x reference)
//
#include <hip/hip_runtime.h>

// Problem constants (fixed by setup_inputs) — float inputs are FP32.
#define NB 8
#define NN 4096
#define DEG 16
#define UN 128
#define NE (NN*DEG)
#define SC 1.2304489f   // fp32(log(17)/log(10))
#define BTILES 64       // 64-node tiles for the dense GEMM kernel
#define BGRID (NB*BTILES)

typedef unsigned short u16;
typedef unsigned char u8;
typedef __attribute__((ext_vector_type(8))) short short8;  // 8 bf16 = 4 VGPRs
typedef __attribute__((ext_vector_type(4))) float f32x4;
typedef __attribute__((ext_vector_type(2))) float f32x2;

#if defined(__has_builtin)
#if __has_builtin(__builtin_amdgcn_cvt_pk_f32_fp8) && __has_builtin(__builtin_amdgcn_cvt_pk_fp8_f32)
#define HAVE_HW_FP8 1
#endif
#endif
#ifndef HAVE_HW_FP8
#define HAVE_HW_FP8 0
#endif

// round-to-nearest-even fp32 -> bf16
__device__ __forceinline__ u16 f2b(float f) {
    unsigned u = __float_as_uint(f);
    unsigned r = ((u >> 16) & 1u) + 0x7FFFu;
    return (u16)((u + r) >> 16);
}

// ---- fp8 e4m3fn (OCP) helpers -------------------------------------------
#if !HAVE_HW_FP8
__device__ __forceinline__ float e4m3_to_f(unsigned b) {
    unsigned s = (b & 0x80u) << 24;
    unsigned e = (b >> 3) & 15u, m = b & 7u;
    float v = e ? __uint_as_float(((e + 120u) << 23) | (m << 20))
                : (float)m * 0.001953125f;  // 2^-9
    return __uint_as_float(__float_as_uint(v) | s);
}
__device__ __forceinline__ u8 f_to_e4m3(float f) {
    float a = fabsf(f);
    unsigned s = __float_as_uint(f) >> 31 ? 0x80u : 0u;
    if (!(a < 448.f)) return (u8)(s | 0x7E);            // saturate
    if (a < 0.015625f) {                                // < 2^-6: subnormal
        int n = (int)rintf(a * 512.f);                  // 0..8
        return (u8)(s | (unsigned)n);
    }
    int ex; float mant = frexpf(a, &ex);                // a = mant*2^ex, mant in [0.5,1)
    int q = (int)rintf(mant * 16.f);                    // 8..16
    if (q == 16) { q = 8; ex++; }
    return (u8)(s | ((unsigned)(ex + 6) << 3) | (unsigned)(q - 8));
}
#endif

// decode 4 fp8 bytes (one u32) -> 4 floats
__device__ __forceinline__ void dec4(unsigned v, float* f) {
#if HAVE_HW_FP8
    f32x2 lo = __builtin_amdgcn_cvt_pk_f32_fp8(v, false);
    f32x2 hi = __builtin_amdgcn_cvt_pk_f32_fp8(v, true);
    f[0] = lo.x; f[1] = lo.y; f[2] = hi.x; f[3] = hi.y;
#else
    f[0] = e4m3_to_f(v & 0xffu);         f[1] = e4m3_to_f((v >> 8) & 0xffu);
    f[2] = e4m3_to_f((v >> 16) & 0xffu); f[3] = e4m3_to_f(v >> 24);
#endif
}
__device__ __forceinline__ u8 enc1(float f) {
#if HAVE_HW_FP8
    return (u8)(__builtin_amdgcn_cvt_pk_fp8_f32(f, f, 0, false) & 0xff);
#else
    return f_to_e4m3(f);
#endif
}
__device__ __forceinline__ unsigned enc4(float a, float b, float c, float d) {
#if HAVE_HW_FP8
    unsigned w = (unsigned)__builtin_amdgcn_cvt_pk_fp8_f32(a, b, 0, false);
    return (unsigned)__builtin_amdgcn_cvt_pk_fp8_f32(c, d, (int)w, true);
#else
    return (unsigned)f_to_e4m3(a) | ((unsigned)f_to_e4m3(b) << 8) |
           ((unsigned)f_to_e4m3(c) << 16) | ((unsigned)f_to_e4m3(d) << 24);
#endif
}

// async global->LDS, 16B/lane, 64 lanes = 1KB per instruction.
// LDS dest = wave-uniform base + lane*16 (linear); global src is per-lane.
#define GLOAD_LDS16(g, l) __builtin_amdgcn_global_load_lds( \
    (const __attribute__((address_space(1))) void*)(g),     \
    (__attribute__((address_space(3))) void*)(l), 16, 0, 0)

// ---------------------------------------------------------------------------
// Prep: fold W -> transposed bf16 B-mats + BN consts; zero batch counters;
// pack edge dst column into u16.
// ---------------------------------------------------------------------------
__global__ void pna12_prep(const float* W, const float* bias, const float* gamma,
                           const float* beta, const float* mmean, const float* mvar,
                           const int* eidx, u16* AsumT, u16* AmaxT, float* biasf,
                           float* kv, float* cv, int* counters, u16* dst16) {
    const int bid = blockIdx.x;
    const int t = threadIdx.x;  // 128
    if (bid == 0 && t < 16) counters[t] = 0;
    const int tid = bid * 128 + t;
    for (int i = tid; i < NB * NE; i += 384 * 128)
        dst16[i] = (u16)(eidx[(size_t)i * 2 + 1] & (NN - 1));
    const int d = bid >> 7;
    const int j = bid & 127;
    const int u = t;
    const float* Wd = W + (size_t)d * 9 * UN * UN;
    float w[9];
#pragma unroll
    for (int r = 0; r < 9; r++) w[r] = Wd[(size_t)(r * UN + j) * UN + u];
    float asum = (w[0] + SC * (w[1] + w[2])) * 0.0625f + w[6] + SC * (w[7] + w[8]);
    float amax = w[3] + SC * (w[4] + w[5]);
    AsumT[((size_t)d * UN + u) * UN + j] = f2b(asum);
    AmaxT[((size_t)d * UN + u) * UN + j] = f2b(amax);
    if (j == 0) {
        float k = gamma[d * UN + u] * rsqrtf(mvar[d * UN + u] + 1e-3f);
        kv[d * UN + u] = k;
        cv[d * UN + u] = beta[d * UN + u] - mmean[d * UN + u] * k;
        biasf[d * UN + u] = bias[d * UN + u];
    }
}

// x fp32 -> fp8 e4m3. grid 2048, block 256: 8 floats/thread, exact cover.
__global__ void pna12_cvt(const float* __restrict__ x, u8* __restrict__ xc) {
    const int i = (blockIdx.x * 256 + threadIdx.x) * 8;
    float4 a = *(const float4*)(x + i);
    float4 c = *(const float4*)(x + i + 4);
    uint2 o = { enc4(a.x, a.y, a.z, a.w), enc4(c.x, c.y, c.z, c.w) };
    *(uint2*)(xc + i) = o;
}

// ---------------------------------------------------------------------------
// Kernel A — aggregate. grid 256 = b(8, XCD pin) x feat-slice(4) x tile(8),
// 1024 threads, 128 KB LDS -> 1 block/CU, full 256-block co-residency.
// Stage the (batch, 32-feat slice) of fp8 x [4096 x 32 B = 128 KB] into LDS
// via global_load_lds (CONTIGUOUS stream — no random global access anywhere),
// then gather this tile's 512 nodes x 16 edges from LDS (ds_read_b64,
// 4 lanes/node, expected 4-way bank conflict = 1.58x, cheap) and write
// per-node SUM/MAX bf16 slices.
// Rationale: r0-r6 varied bytes (fp32/bf16/fp8), occupancy (16->32 waves/CU)
// and per-wave load depth (2..16) — per-layer time pinned at 43-50us with all
// pipes idle. The random-global-gather path is ~10-25x slower than any
// latency model; this kernel removes it instead of modeling it.
// ---------------------------------------------------------------------------
__global__ __launch_bounds__(1024, 4) void pna12_agg(
        const u8* __restrict__ xin, const u16* __restrict__ dst16,
        u16* __restrict__ Sg, u16* __restrict__ Mg) {
    const int bid = blockIdx.x;
    const int b = bid & 7;             // batch -> XCD pin
    const int sl = (bid >> 3) & 3;     // feature slice (32 feats)
    const int tile = bid >> 5;         // node tile (512 nodes)
    const int t = threadIdx.x;         // 1024
    const int w = t >> 6, lane = t & 63;

    __shared__ u8 xs[NN * 32];         // 128 KB

    // ---- stage slice: 16 waves x 8 iters x 1KB (global_load_lds w=16) ----
    const u8* xb = xin + (size_t)b * NN * UN + sl * 32;
#pragma unroll
    for (int k = 0; k < 8; k++) {
        const int chunk = (w * 8 + k) * 64 + lane;   // 0..8191 (16B chunks)
        const int v = chunk >> 1, h = chunk & 1;
        GLOAD_LDS16(xb + (size_t)v * UN + h * 16, &xs[(w * 8 + k) * 1024]);
    }
    asm volatile("s_waitcnt vmcnt(0)" ::: "memory");
    __syncthreads();

    // ---- gather from LDS: 32 nodes/wave, 4 lanes/node (8 feats), 2 passes
    const int fc = lane & 3;
#pragma unroll
    for (int p = 0; p < 2; p++) {
        const int node = tile * 512 + w * 32 + p * 16 + (lane >> 2);
        const u16* ip = dst16 + (size_t)b * NE + (size_t)node * DEG;  // L1-hot
        float s[8], m[8];
#pragma unroll
        for (int c = 0; c < 8; c++) { s[c] = 0.f; m[c] = -1e30f; }
#pragma unroll
        for (int e = 0; e < DEG; e++) {
            const unsigned idx = ip[e];
            uint2 r = *(const uint2*)(&xs[idx * 32 + fc * 8]);
            float f[8];
            dec4(r.x, f);
            dec4(r.y, f + 4);
#pragma unroll
            for (int c = 0; c < 8; c++) {
                s[c] += f[c];
                m[c] = fmaxf(m[c], f[c]);
            }
        }
        u16 os[8], om[8];
#pragma unroll
        for (int c = 0; c < 8; c++) { os[c] = f2b(s[c]); om[c] = f2b(m[c]); }
        const size_t o = ((size_t)b * NN + node) * UN + sl * 32 + fc * 8;
        *(uint4*)(Sg + o) = *(const uint4*)os;
        *(uint4*)(Mg + o) = *(const uint4*)om;
    }
}

// ---------------------------------------------------------------------------
// Kernel B — dense transform (no randomness). grid 512 = b(8, XCD pin) x
// tile(64 nodes), block 256. C = S·Asum + M·Amax (K=128+128, the /16 mean
// fold is inside Asum), fused bias/ReLU/BN -> fp8 x_next.
// A-frags read straight from global Sg/Mg (L2-resident: 2 MB/batch on the
// pinned XCD); B-frags from AsumT/AmaxT (L1/L2-hot). Same verified MFMA
// fragment mapping as r0-r6. MODE 2: fused readout + last-block MLP.
// ---------------------------------------------------------------------------
template <int MODE>
__global__ __launch_bounds__(256, 4) void pna12_gemm(
        const u16* __restrict__ Sg, const u16* __restrict__ Mg,
        const u16* __restrict__ AsumT, const u16* __restrict__ AmaxT,
        const float* __restrict__ biasf, const float* __restrict__ kv,
        const float* __restrict__ cv,
        u8* __restrict__ xout, float* __restrict__ partial,
        int* __restrict__ counters,
        const float* __restrict__ Wp1, const float* __restrict__ bp1,
        const float* __restrict__ Wp2, const float* __restrict__ bp2,
        float* __restrict__ out, int d) {
    const int bid = blockIdx.x;
    const int b = bid & 7;               // batch -> XCD pin
    const int tile = bid >> 3;           // 0..63
    const int node0 = tile * 64;
    const int t = threadIdx.x;           // 256
    const int w = t >> 6, lane = t & 63;
    const int l15 = lane & 15, quad = lane >> 4;

    __shared__ u8 s8[64 * UN];           // 8 KB epilogue staging
    __shared__ float red[4 * UN];        // MODE2 per-quad partial
    __shared__ float gmean_s[UN];
    __shared__ float mlp1[UN];
    __shared__ int is_last;

    const u16* Bs = AsumT + (size_t)d * UN * UN;
    const u16* Bm = AmaxT + (size_t)d * UN * UN;
    const u16* Sb = Sg + ((size_t)b * NN + node0) * UN;
    const u16* Mb = Mg + ((size_t)b * NN + node0) * UN;

    f32x4 acc[4][2] = {};
#pragma unroll
    for (int msub = 0; msub < 4; msub++) {
#pragma unroll
        for (int k0 = 0; k0 < 4; k0++) {
            short8 aS = *(const short8*)(Sb + (size_t)(msub * 16 + l15) * UN + k0 * 32 + quad * 8);
            short8 aM = *(const short8*)(Mb + (size_t)(msub * 16 + l15) * UN + k0 * 32 + quad * 8);
#pragma unroll
            for (int nt = 0; nt < 2; nt++) {
                const int ng = w * 2 + nt;
                short8 bS = *(const short8*)(Bs + (size_t)(ng * 16 + l15) * UN + k0 * 32 + quad * 8);
                short8 bM = *(const short8*)(Bm + (size_t)(ng * 16 + l15) * UN + k0 * 32 + quad * 8);
                acc[msub][nt] = __builtin_amdgcn_mfma_f32_16x16x32_bf16(aS, bS, acc[msub][nt], 0, 0, 0);
                acc[msub][nt] = __builtin_amdgcn_mfma_f32_16x16x32_bf16(aM, bM, acc[msub][nt], 0, 0, 0);
            }
        }
    }

    if (MODE < 2) {
        // epilogue: y = relu(acc+bias)*k + c -> fp8 via LDS staging.
        // C-map: node = msub*16 + quad*4 + r, unit = ng*16 + l15.
#pragma unroll
        for (int nt = 0; nt < 2; nt++) {
            const int u = (w * 2 + nt) * 16 + l15;
            const float bb = biasf[d * UN + u], kk = kv[d * UN + u], cc = cv[d * UN + u];
#pragma unroll
            for (int msub = 0; msub < 4; msub++)
#pragma unroll
                for (int r = 0; r < 4; r++) {
                    float y = fmaxf(acc[msub][nt][r] + bb, 0.0f) * kk + cc;
                    s8[(msub * 16 + quad * 4 + r) * UN + u] = enc1(y);
                }
        }
        __syncthreads();
        {
            const int r = t >> 2;              // 64 rows
            const int c0 = (t & 3) * 32;       // 4 threads x 32B = 128B row
            u8* dst = xout + ((size_t)b * NN + node0 + r) * UN + c0;
            *(uint4*)dst = *(const uint4*)(&s8[r * UN + c0]);
            *(uint4*)(dst + 16) = *(const uint4*)(&s8[r * UN + c0 + 16]);
        }
    } else {
        // fused readout stage 1: per-unit sum over tile's 64 nodes
#pragma unroll
        for (int nt = 0; nt < 2; nt++) {
            const int u = (w * 2 + nt) * 16 + l15;
            const float bb = biasf[d * UN + u], kk = kv[d * UN + u], cc = cv[d * UN + u];
            float s = 0.0f;
#pragma unroll
            for (int msub = 0; msub < 4; msub++)
#pragma unroll
                for (int r = 0; r < 4; r++)
                    s += fmaxf(acc[msub][nt][r] + bb, 0.0f) * kk + cc;
            red[quad * UN + u] = s;
        }
        __syncthreads();
        if (t < UN) {
            float s = red[t] + red[UN + t] + red[2 * UN + t] + red[3 * UN + t];
            partial[((size_t)b * BTILES + tile) * UN + t] = s;
        }
        __syncthreads();
        if (t == 0) {
            __threadfence();                       // release partial stores
            int old = atomicAdd(&counters[b], 1);  // device-scope
            is_last = (old == BTILES - 1);
        }
        __syncthreads();
        if (is_last) {
            __threadfence();                       // acquire other tiles' partials
            if (t < UN) {
                float s = 0.0f;
                for (int c = 0; c < BTILES; c++)
                    s += partial[((size_t)b * BTILES + c) * UN + t];
                gmean_s[t] = s * (1.0f / (float)NN);
            }
            __syncthreads();
            if (t < UN) {
                float a = bp1[t];
                for (int j = 0; j < UN; j++)
                    a += gmean_s[j] * Wp1[j * UN + t];
                mlp1[t] = fmaxf(a, 0.0f);
            }
            __syncthreads();
            if (t < 64) {
                float o = bp2[t];
                for (int j = 0; j < UN; j++)
                    o += mlp1[j] * Wp2[j * 64 + t];
                out[b * 64 + t] = fmaxf(o, 0.0f);
            }
        }
    }
}

extern "C" void kernel_launch(void* const* d_in, const int* in_sizes, int n_in,
                              void* d_out, int out_size, void* d_ws, size_t ws_size,
                              hipStream_t stream) {
    const float* xattr = (const float*)d_in[0];   // [8,4096,128] fp32
    const int*   eidx  = (const int*)d_in[1];     // [8,65536,2] int32
    const float* W     = (const float*)d_in[2];   // [3,1152,128] fp32
    const float* bias  = (const float*)d_in[3];
    const float* gamma = (const float*)d_in[4];
    const float* beta  = (const float*)d_in[5];
    const float* mmean = (const float*)d_in[6];
    const float* mvar  = (const float*)d_in[7];
    const float* Wp1   = (const float*)d_in[8];   // [128,128]
    const float* bp1   = (const float*)d_in[9];
    const float* Wp2   = (const float*)d_in[10];  // [128,64]
    const float* bp2   = (const float*)d_in[11];
    float* out = (float*)d_out;                   // [8,64] fp32

    u16* AsumT = (u16*)d_ws;                        // 3*128*128 bf16
    u16* AmaxT = AsumT + 3 * UN * UN;               // 3*128*128 bf16
    float* biasf = (float*)(AmaxT + 3 * UN * UN);   // 3*128 fp32
    float* kv = biasf + 3 * UN;
    float* cv = kv + 3 * UN;
    int* counters = (int*)(cv + 3 * UN);            // 16 ints
    float* partial = (float*)(counters + 16);       // [8,64,128] fp32
    u16* Sg = (u16*)(partial + (size_t)NB * BTILES * UN);  // [8,4096,128] bf16
    u16* Mg = Sg + (size_t)NB * NN * UN;            // [8,4096,128] bf16
    u8* buf0 = (u8*)(Mg + (size_t)NB * NN * UN);    // [8,4096,128] fp8
    u8* buf1 = buf0 + (size_t)NB * NN * UN;         // fp8 (holds x-cvt for layer 0)
    u16* dst16 = (u16*)(buf1 + (size_t)NB * NN * UN); // [8,65536] u16 packed dst

    pna12_prep<<<384, 128, 0, stream>>>(W, bias, gamma, beta, mmean, mvar, eidx,
                                        AsumT, AmaxT, biasf, kv, cv, counters, dst16);
    pna12_cvt<<<2048, 256, 0, stream>>>(xattr, buf1);

    // layer 0: x = buf1 -> Sg/Mg -> x_next = buf0
    pna12_agg<<<256, 1024, 0, stream>>>(buf1, dst16, Sg, Mg);
    pna12_gemm<1><<<BGRID, 256, 0, stream>>>(Sg, Mg, AsumT, AmaxT, biasf, kv, cv,
                                             buf0, partial, counters,
                                             Wp1, bp1, Wp2, bp2, out, 0);
    // layer 1: buf0 -> buf1
    pna12_agg<<<256, 1024, 0, stream>>>(buf0, dst16, Sg, Mg);
    pna12_gemm<1><<<BGRID, 256, 0, stream>>>(Sg, Mg, AsumT, AmaxT, biasf, kv, cv,
                                             buf1, partial, counters,
                                             Wp1, bp1, Wp2, bp2, out, 1);
    // layer 2: buf1 -> fused readout
    pna12_agg<<<256, 1024, 0, stream>>>(buf1, dst16, Sg, Mg);
    pna12_gemm<2><<<BGRID, 256, 0, stream>>>(Sg, Mg, AsumT, AmaxT, biasf, kv, cv,
                                             (u8*)nullptr, partial, counters,
                                             Wp1, bp1, Wp2, bp2, out, 2);
}

// Round 8
// 150.262 us; speedup vs baseline: 1.2269x; 1.2269x over previous
//
#include <hip/hip_runtime.h>

// Problem constants (fixed by setup_inputs) — float inputs are FP32.
#define NB 8
#define NN 4096
#define DEG 16
#define UN 128
#define NE (NN*DEG)
#define SC 1.2304489f   // fp32(log(17)/log(10))
#define TILES 128       // 32-node tiles (r3: 16-node tiles double per-block fixed cost)
#define GRID (NB*TILES) // 1024 = 4 blocks/CU * 256 CUs -> full co-residency, bid&7 XCD pin

typedef unsigned short u16;
typedef unsigned char u8;
typedef __attribute__((ext_vector_type(8))) short short8;  // 8 bf16 = 4 VGPRs
typedef __attribute__((ext_vector_type(4))) float f32x4;
typedef __attribute__((ext_vector_type(2))) float f32x2;

#if defined(__has_builtin)
#if __has_builtin(__builtin_amdgcn_cvt_pk_f32_fp8) && __has_builtin(__builtin_amdgcn_cvt_pk_fp8_f32)
#define HAVE_HW_FP8 1
#endif
#endif
#ifndef HAVE_HW_FP8
#define HAVE_HW_FP8 0
#endif

// round-to-nearest-even fp32 -> bf16
__device__ __forceinline__ u16 f2b(float f) {
    unsigned u = __float_as_uint(f);
    unsigned r = ((u >> 16) & 1u) + 0x7FFFu;
    return (u16)((u + r) >> 16);
}

// ---- fp8 e4m3fn (OCP) helpers -------------------------------------------
#if !HAVE_HW_FP8
__device__ __forceinline__ float e4m3_to_f(unsigned b) {
    unsigned s = (b & 0x80u) << 24;
    unsigned e = (b >> 3) & 15u, m = b & 7u;
    float v = e ? __uint_as_float(((e + 120u) << 23) | (m << 20))
                : (float)m * 0.001953125f;  // 2^-9
    return __uint_as_float(__float_as_uint(v) | s);
}
__device__ __forceinline__ u8 f_to_e4m3(float f) {
    float a = fabsf(f);
    unsigned s = __float_as_uint(f) >> 31 ? 0x80u : 0u;
    if (!(a < 448.f)) return (u8)(s | 0x7E);            // saturate
    if (a < 0.015625f) {                                // < 2^-6: subnormal
        int n = (int)rintf(a * 512.f);                  // 0..8
        return (u8)(s | (unsigned)n);
    }
    int ex; float mant = frexpf(a, &ex);                // a = mant*2^ex, mant in [0.5,1)
    int q = (int)rintf(mant * 16.f);                    // 8..16
    if (q == 16) { q = 8; ex++; }
    return (u8)(s | ((unsigned)(ex + 6) << 3) | (unsigned)(q - 8));
}
#endif

// decode 4 fp8 bytes (one u32) -> 4 floats
__device__ __forceinline__ void dec4(unsigned v, float* f) {
#if HAVE_HW_FP8
    f32x2 lo = __builtin_amdgcn_cvt_pk_f32_fp8(v, false);
    f32x2 hi = __builtin_amdgcn_cvt_pk_f32_fp8(v, true);
    f[0] = lo.x; f[1] = lo.y; f[2] = hi.x; f[3] = hi.y;
#else
    f[0] = e4m3_to_f(v & 0xffu);         f[1] = e4m3_to_f((v >> 8) & 0xffu);
    f[2] = e4m3_to_f((v >> 16) & 0xffu); f[3] = e4m3_to_f(v >> 24);
#endif
}
__device__ __forceinline__ u8 enc1(float f) {
#if HAVE_HW_FP8
    return (u8)(__builtin_amdgcn_cvt_pk_fp8_f32(f, f, 0, false) & 0xff);
#else
    return f_to_e4m3(f);
#endif
}
__device__ __forceinline__ unsigned enc4(float a, float b, float c, float d) {
#if HAVE_HW_FP8
    unsigned w = (unsigned)__builtin_amdgcn_cvt_pk_fp8_f32(a, b, 0, false);
    return (unsigned)__builtin_amdgcn_cvt_pk_fp8_f32(c, d, (int)w, true);
#else
    return (unsigned)f_to_e4m3(a) | ((unsigned)f_to_e4m3(b) << 8) |
           ((unsigned)f_to_e4m3(c) << 16) | ((unsigned)f_to_e4m3(d) << 24);
#endif
}

// ---------------------------------------------------------------------------
// Prep: fold W -> FRAGMENT-ORDER bf16 B-mats + BN consts; zero counters;
// pack edge dst column into u16.
// B layout change (r8): old AsumT[d][u][j] made every MFMA B-frag load touch
// 16 distinct 64B lines (16 lanes x stride 256B) — 2048 scattered lines per
// block per layer, 2x the gather itself, thrashing L1. New layout
// Bp[d][ng][k0][lane][8] puts each lane's 8 bf16 at base + lane*16:
// every B-frag load is one dense 1KB instruction.
//   mapping: u = ng*16 + (lane&15), j = k0*32 + (lane>>4)*8 + jj
//   Asum = (W0+s(W1+W2))/16 + W6+s(W7+W8), Amax = W3+s(W4+W5)  (transposed)
//   k = gamma*rsqrt(var+eps), c = beta - mean*k
// grid 384 (d,j), block 128 (u).
// ---------------------------------------------------------------------------
__global__ void pna12_prep(const float* W, const float* bias, const float* gamma,
                           const float* beta, const float* mmean, const float* mvar,
                           const int* eidx, u16* AsumT, u16* AmaxT, float* biasf,
                           float* kv, float* cv, int* counters, u16* dst16) {
    const int bid = blockIdx.x;
    const int t = threadIdx.x;  // 128
    if (bid == 0 && t < 16) counters[t] = 0;
    const int tid = bid * 128 + t;
    for (int i = tid; i < NB * NE; i += 384 * 128)
        dst16[i] = (u16)(eidx[(size_t)i * 2 + 1] & (NN - 1));
    const int d = bid >> 7;
    const int j = bid & 127;
    const int u = t;
    const float* Wd = W + (size_t)d * 9 * UN * UN;
    float w[9];
#pragma unroll
    for (int r = 0; r < 9; r++) w[r] = Wd[(size_t)(r * UN + j) * UN + u];
    float asum = (w[0] + SC * (w[1] + w[2])) * 0.0625f + w[6] + SC * (w[7] + w[8]);
    float amax = w[3] + SC * (w[4] + w[5]);
    // fragment-order address: lane = quad*16 + l15
    const int ng = u >> 4, l15v = u & 15;
    const int k0 = j >> 5, qd = (j >> 3) & 3, jj = j & 7;
    const size_t po = ((((size_t)d * 8 + ng) * 4 + k0) * 64 + qd * 16 + l15v) * 8 + jj;
    AsumT[po] = f2b(asum);
    AmaxT[po] = f2b(amax);
    if (j == 0) {
        float k = gamma[d * UN + u] * rsqrtf(mvar[d * UN + u] + 1e-3f);
        kv[d * UN + u] = k;
        cv[d * UN + u] = beta[d * UN + u] - mmean[d * UN + u] * k;
        biasf[d * UN + u] = bias[d * UN + u];
    }
}

// x fp32 -> fp8 e4m3. grid 2048, block 256: 8 floats/thread, exact cover.
__global__ void pna12_cvt(const float* __restrict__ x, u8* __restrict__ xc) {
    const int i = (blockIdx.x * 256 + threadIdx.x) * 8;
    float4 a = *(const float4*)(x + i);
    float4 c = *(const float4*)(x + i + 4);
    uint2 o = { enc4(a.x, a.y, a.z, a.w), enc4(c.x, c.y, c.z, c.w) };
    *(uint2*)(xc + i) = o;
}

// ---------------------------------------------------------------------------
// PNA layer (r6 champion structure + dense B loads). grid 1024 (b = bid&7
// XCD-pin, 32-node tile), block 256, 4 blk/CU.
// x stored fp8 e4m3 -> each edge-row is 128 B = 2 cache lines.
// r0-r7 model: cost ~ scattered-64B-lines per CU (~8.6 cyc/line TA/TCP tax);
// bytes, occupancy, per-wave depth all null. This round removes the B-frag
// scatter (2048 lines/block -> dense 1KB loads); gather scatter (1024
// lines/block) is irreducible without reordering edges.
// MODE 1: fp8 -> fp8; MODE 2: fp8 -> fused readout + MLP.
// ---------------------------------------------------------------------------
template <int MODE>
__global__ __launch_bounds__(256, 4) void pna12_layer(
        const u8* __restrict__ xin, const u16* __restrict__ dst16,
        const u16* __restrict__ AsumT, const u16* __restrict__ AmaxT,
        const float* __restrict__ biasf, const float* __restrict__ kv,
        const float* __restrict__ cv,
        u8* __restrict__ xout, float* __restrict__ partial,
        int* __restrict__ counters,
        const float* __restrict__ Wp1, const float* __restrict__ bp1,
        const float* __restrict__ Wp2, const float* __restrict__ bp2,
        float* __restrict__ out, int d) {
    const int bid = blockIdx.x;
    const int b = bid & 7;               // batch -> XCD pin
    const int tile = bid >> 3;           // 0..127
    const int node0 = tile * 32;
    const int t = threadIdx.x;           // 256
    const int w = t >> 6, lane = t & 63;
    const int l15 = lane & 15, quad = lane >> 4;

    __shared__ alignas(16) u16 sS[32][136];  // s_sum bf16 (row stride 272 B)
    __shared__ alignas(16) u16 sM[32][136];  // s_max bf16 / fp8-out staging / red
    __shared__ u16 sidx[32 * DEG];           // 512 edge dsts (u16) = 256 uints
    __shared__ float gmean_s[UN];
    __shared__ float mlp1[UN];
    __shared__ int is_last;

    ((uint*)sidx)[t] = ((const uint*)(dst16 + (size_t)b * NE + node0 * DEG))[t];
    __syncthreads();

    // ---- gather: 8 nodes/wave (4 per it, quad-mapped), fp8 rows ----------
    {
        const u8* xb = xin + (size_t)b * NN * UN;
#pragma unroll
        for (int it = 0; it < 2; it++) {
            const int nl = w * 8 + it * 4 + quad;
            const u16* ip = sidx + nl * DEG;
            float s[8], m[8];
#pragma unroll
            for (int c = 0; c < 8; c++) { s[c] = 0.f; m[c] = -1e30f; }
#pragma unroll
            for (int e = 0; e < 16; e++) {
                uint2 r = *(const uint2*)(xb + (size_t)ip[e] * UN + l15 * 8);
                float f[8];
                dec4(r.x, f);
                dec4(r.y, f + 4);
#pragma unroll
                for (int c = 0; c < 8; c++) {
                    s[c] += f[c];
                    m[c] = fmaxf(m[c], f[c]);
                }
            }
            u16 os[8], om[8];
#pragma unroll
            for (int c = 0; c < 8; c++) { os[c] = f2b(s[c]); om[c] = f2b(m[c]); }
            *(uint4*)(&sS[nl][l15 * 8]) = *(const uint4*)os;
            *(uint4*)(&sM[nl][l15 * 8]) = *(const uint4*)om;
        }
    }
    __syncthreads();

    // MFMA: wave w -> units [w*32,+32) (ng = 2w,2w+1), m-subtiles 0,1.
    // B loads are fragment-order: base + lane*16, one dense 1KB per instr.
    const u16* Bs = AsumT + (size_t)d * UN * UN;
    const u16* Bm = AmaxT + (size_t)d * UN * UN;
    f32x4 acc[2][2] = {};
#pragma unroll
    for (int msub = 0; msub < 2; msub++) {
#pragma unroll
        for (int k0 = 0; k0 < 4; k0++) {
            short8 aS = *(const short8*)(&sS[msub * 16 + l15][k0 * 32 + quad * 8]);
            short8 aM = *(const short8*)(&sM[msub * 16 + l15][k0 * 32 + quad * 8]);
#pragma unroll
            for (int nt = 0; nt < 2; nt++) {
                const int ng = w * 2 + nt;
                const size_t bo = (((size_t)ng * 4 + k0) * 64 + lane) * 8;
                short8 bS = *(const short8*)(Bs + bo);
                short8 bM = *(const short8*)(Bm + bo);
                acc[msub][nt] = __builtin_amdgcn_mfma_f32_16x16x32_bf16(aS, bS, acc[msub][nt], 0, 0, 0);
                acc[msub][nt] = __builtin_amdgcn_mfma_f32_16x16x32_bf16(aM, bM, acc[msub][nt], 0, 0, 0);
            }
        }
    }

    if (MODE < 2) {
        // epilogue: y = relu(acc+bias)*k + c -> fp8 via LDS staging.
        // C-map: node = msub*16 + quad*4 + r, unit = ng*16 + l15.
        __syncthreads();
        u8* s8 = (u8*)sM;    // [32][128] fp8 staging (4 KB <= sM)
#pragma unroll
        for (int nt = 0; nt < 2; nt++) {
            const int u = (w * 2 + nt) * 16 + l15;
            const float bb = biasf[d * UN + u], kk = kv[d * UN + u], cc = cv[d * UN + u];
#pragma unroll
            for (int msub = 0; msub < 2; msub++)
#pragma unroll
                for (int r = 0; r < 4; r++) {
                    float y = fmaxf(acc[msub][nt][r] + bb, 0.0f) * kk + cc;
                    s8[(msub * 16 + quad * 4 + r) * UN + u] = enc1(y);
                }
        }
        __syncthreads();
        {
            int r = t >> 3;            // 32 rows
            int c0 = (t & 7) * 16;     // 8 threads x 16B = 128B row
            *(uint4*)(xout + ((size_t)b * NN + node0 + r) * UN + c0) =
                *(const uint4*)(&s8[r * UN + c0]);
        }
    } else {
        // fused readout stage 1: per-unit sum over tile's 32 nodes
        float* red = (float*)sM;   // [4 quads][128 units] fp32
        __syncthreads();
#pragma unroll
        for (int nt = 0; nt < 2; nt++) {
            const int u = (w * 2 + nt) * 16 + l15;
            const float bb = biasf[d * UN + u], kk = kv[d * UN + u], cc = cv[d * UN + u];
            float s = 0.0f;
#pragma unroll
            for (int msub = 0; msub < 2; msub++)
#pragma unroll
                for (int r = 0; r < 4; r++)
                    s += fmaxf(acc[msub][nt][r] + bb, 0.0f) * kk + cc;
            red[quad * UN + u] = s;
        }
        __syncthreads();
        if (t < UN) {
            float s = red[t] + red[UN + t] + red[2 * UN + t] + red[3 * UN + t];
            partial[((size_t)b * TILES + tile) * UN + t] = s;
        }
        __syncthreads();
        if (t == 0) {
            __threadfence();                       // release partial stores
            int old = atomicAdd(&counters[b], 1);  // device-scope
            is_last = (old == TILES - 1);
        }
        __syncthreads();
        if (is_last) {
            __threadfence();                       // acquire other tiles' partials
            if (t < UN) {
                float s = 0.0f;
                for (int c = 0; c < TILES; c++)
                    s += partial[((size_t)b * TILES + c) * UN + t];
                gmean_s[t] = s * (1.0f / (float)NN);
            }
            __syncthreads();
            if (t < UN) {
                float a = bp1[t];
                for (int j = 0; j < UN; j++)
                    a += gmean_s[j] * Wp1[j * UN + t];
                mlp1[t] = fmaxf(a, 0.0f);
            }
            __syncthreads();
            if (t < 64) {
                float o = bp2[t];
                for (int j = 0; j < UN; j++)
                    o += mlp1[j] * Wp2[j * 64 + t];
                out[b * 64 + t] = fmaxf(o, 0.0f);
            }
        }
    }
}

extern "C" void kernel_launch(void* const* d_in, const int* in_sizes, int n_in,
                              void* d_out, int out_size, void* d_ws, size_t ws_size,
                              hipStream_t stream) {
    const float* xattr = (const float*)d_in[0];   // [8,4096,128] fp32
    const int*   eidx  = (const int*)d_in[1];     // [8,65536,2] int32
    const float* W     = (const float*)d_in[2];   // [3,1152,128] fp32
    const float* bias  = (const float*)d_in[3];
    const float* gamma = (const float*)d_in[4];
    const float* beta  = (const float*)d_in[5];
    const float* mmean = (const float*)d_in[6];
    const float* mvar  = (const float*)d_in[7];
    const float* Wp1   = (const float*)d_in[8];   // [128,128]
    const float* bp1   = (const float*)d_in[9];
    const float* Wp2   = (const float*)d_in[10];  // [128,64]
    const float* bp2   = (const float*)d_in[11];
    float* out = (float*)d_out;                   // [8,64] fp32

    u16* AsumT = (u16*)d_ws;                        // 3*128*128 bf16 (fragment order)
    u16* AmaxT = AsumT + 3 * UN * UN;               // 3*128*128 bf16 (fragment order)
    float* biasf = (float*)(AmaxT + 3 * UN * UN);   // 3*128 fp32
    float* kv = biasf + 3 * UN;
    float* cv = kv + 3 * UN;
    int* counters = (int*)(cv + 3 * UN);            // 16 ints
    float* partial = (float*)(counters + 16);       // [8,128,128] fp32
    u8* buf0 = (u8*)(partial + (size_t)NB * TILES * UN);  // [8,4096,128] fp8
    u8* buf1 = buf0 + (size_t)NB * NN * UN;         // fp8 (holds x-cvt for layer 0)
    u16* dst16 = (u16*)(buf1 + (size_t)NB * NN * UN); // [8,65536] u16 packed dst

    pna12_prep<<<384, 128, 0, stream>>>(W, bias, gamma, beta, mmean, mvar, eidx,
                                        AsumT, AmaxT, biasf, kv, cv, counters, dst16);
    pna12_cvt<<<2048, 256, 0, stream>>>(xattr, buf1);
    pna12_layer<1><<<GRID, 256, 0, stream>>>(buf1, dst16, AsumT, AmaxT, biasf, kv, cv,
                                             buf0, partial, counters,
                                             Wp1, bp1, Wp2, bp2, out, 0);
    pna12_layer<1><<<GRID, 256, 0, stream>>>(buf0, dst16, AsumT, AmaxT, biasf, kv, cv,
                                             buf1, partial, counters,
                                             Wp1, bp1, Wp2, bp2, out, 1);
    pna12_layer<2><<<GRID, 256, 0, stream>>>(buf1, dst16, AsumT, AmaxT, biasf, kv, cv,
                                             (u8*)nullptr, partial, counters,
                                             Wp1, bp1, Wp2, bp2, out, 2);
}